// Round 1
// baseline (7129.408 us; speedup 1.0000x reference)
//
#include <hip/hip_runtime.h>
#include <stdint.h>

#define B_ 4
#define N_ 5000
#define T_ 12
#define FH_ 12
#define H_ 128
#define BN_ 20000
#define E_ 320000
#define TOTE_ (E_ + BN_)

__device__ __forceinline__ float fast_tanh(float x) {
  float e = __expf(2.f * x);
  return 1.f - 2.f * __builtin_amdgcn_rcpf(e + 1.f);
}
__device__ __forceinline__ float fast_sigmoid(float x) {
  return __builtin_amdgcn_rcpf(1.f + __expf(-x));
}

__global__ void k_sentinel(float* out) { out[0] = 1e30f; }

__global__ void k_init_cnt(int* cnt) {
  int i = blockIdx.x * 256 + threadIdx.x;
  if (i < BN_) cnt[i] = 1;  // self-loop
}

__global__ void k_count(const int* __restrict__ dst, int* cnt) {
  int e = blockIdx.x * 256 + threadIdx.x;
  if (e < E_) atomicAdd(&cnt[dst[e]], 1);
}

__global__ void k_dinv(const int* __restrict__ cnt, float* __restrict__ dinv) {
  int i = blockIdx.x * 256 + threadIdx.x;
  if (i < BN_) dinv[i] = rsqrtf((float)cnt[i]);
}

// exclusive scan of cnt[BN_] -> rp[BN_+1]; zeroes cnt afterwards (reused as fill ctr)
__global__ void k_scan(int* cnt, int* rp) {
  __shared__ int sh[1024];
  int tid = threadIdx.x;
  const int per = (BN_ + 1023) / 1024;  // 20
  int start = tid * per;
  int end = start + per; if (end > BN_) end = BN_;
  int s = 0;
  for (int i = start; i < end; i++) s += cnt[i];
  sh[tid] = s;
  __syncthreads();
  for (int off = 1; off < 1024; off <<= 1) {
    int v = (tid >= off) ? sh[tid - off] : 0;
    __syncthreads();
    sh[tid] += v;
    __syncthreads();
  }
  int run = (tid > 0) ? sh[tid - 1] : 0;
  for (int i = start; i < end; i++) {
    int c = cnt[i];
    rp[i] = run;
    run += c;
    cnt[i] = 0;
  }
  if (tid == 1023) rp[BN_] = sh[1023];
}

__global__ void k_fill(const int* __restrict__ src, const int* __restrict__ dst,
                       const int* __restrict__ rp, int* cnt, int* ci,
                       float* val, const float* __restrict__ dinv) {
  int e = blockIdx.x * 256 + threadIdx.x;
  if (e >= TOTE_) return;
  int s, d;
  if (e < E_) { s = src[e]; d = dst[e]; }
  else { s = d = e - E_; }  // self loop
  int pos = rp[d] + atomicAdd(&cnt[d], 1);
  ci[pos] = s;
  val[pos] = dinv[s] * dinv[d];
}

// transpose gru_w_ih (384,128) -> (128,384) so the GEMM is always k-major
__global__ void k_tw(const float* __restrict__ w, float* __restrict__ wt) {
  int idx = blockIdx.x * 256 + threadIdx.x;
  if (idx >= 384 * 128) return;
  int c = idx >> 7, k = idx & 127;
  wt[k * 384 + c] = w[idx];
}

__global__ void k_spmv1(const int* __restrict__ rp, const int* __restrict__ ci,
                        const float* __restrict__ val, const float* __restrict__ x,
                        int t, float* __restrict__ out) {
  int r = blockIdx.x * 256 + threadIdx.x;
  if (r >= BN_) return;
  float a = 0.f;
  int beg = rp[r], end = rp[r + 1];
  for (int e = beg; e < end; e++) a = fmaf(val[e], x[(size_t)ci[e] * T_ + t], a);
  out[r] = a;
}

__global__ void k_layer1(const float* __restrict__ agg, const float* __restrict__ w1,
                         const float* __restrict__ b1, float* __restrict__ h1) {
  int idx = blockIdx.x * 256 + threadIdx.x;
  if (idx >= BN_ * 64) return;
  int r = idx >> 6, j = idx & 63;
  float v = fmaf(agg[r], w1[j], b1[j]);
  h1[idx] = fmaxf(v, 0.f);
}

template<int WF>
__global__ void k_spmm(const int* __restrict__ rp, const int* __restrict__ ci,
                       const float* __restrict__ val, const float* __restrict__ in,
                       float* __restrict__ out) {
  int wid = (blockIdx.x * blockDim.x + threadIdx.x) >> 6;
  int lane = threadIdx.x & 63;
  if (wid >= BN_) return;
  int beg = rp[wid], end = rp[wid + 1];
  if (WF == 128) {
    float ax = 0.f, ay = 0.f;
    for (int e = beg; e < end; e++) {
      int s = ci[e]; float v = val[e];
      float2 a = ((const float2*)(in + (size_t)s * 128))[lane];
      ax = fmaf(v, a.x, ax); ay = fmaf(v, a.y, ay);
    }
    float2 o; o.x = ax; o.y = ay;
    ((float2*)(out + (size_t)wid * 128))[lane] = o;
  } else {
    float a = 0.f;
    for (int e = beg; e < end; e++)
      a = fmaf(val[e], in[(size_t)ci[e] * 64 + lane], a);
    out[(size_t)wid * 64 + lane] = a;
  }
}

// C[nrows x OC] = act(A[nrows x K] @ W[K x wld (k-major slice at cbase)] + bias)
// block: 64 rows x 128 cols, 256 threads, each 8 rows x 4 cols
template<int K, int ACT>
__global__ __launch_bounds__(256) void k_gemm(const float* __restrict__ A,
                                              const float* __restrict__ W,
                                              const float* __restrict__ bias,
                                              float* __restrict__ out,
                                              int nrows, int wld, int ldout) {
  __shared__ float As[64][K];
  const int tid = threadIdx.x;
  const int rb = blockIdx.x * 64;
  const int cbase = blockIdx.y * 128;
  const int k4s = K / 4;
  for (int idx = tid; idx < 64 * k4s; idx += 256) {
    int r = idx / k4s, k4 = idx % k4s;
    int row = rb + r;
    float4 v = make_float4(0.f, 0.f, 0.f, 0.f);
    if (row < nrows) v = ((const float4*)(A + (size_t)row * K))[k4];
    ((float4*)&As[r][0])[k4] = v;
  }
  __syncthreads();
  const int cg = tid & 31, rg = tid >> 5;
  const int c0 = cbase + cg * 4;
  const int r0 = rg * 8;
  float acc[8][4];
#pragma unroll
  for (int i = 0; i < 8; i++)
#pragma unroll
    for (int j = 0; j < 4; j++) acc[i][j] = 0.f;

  for (int k = 0; k < K; k += 4) {
    float4 w0 = *(const float4*)(W + (size_t)(k + 0) * wld + c0);
    float4 w1 = *(const float4*)(W + (size_t)(k + 1) * wld + c0);
    float4 w2 = *(const float4*)(W + (size_t)(k + 2) * wld + c0);
    float4 w3 = *(const float4*)(W + (size_t)(k + 3) * wld + c0);
#pragma unroll
    for (int i = 0; i < 8; i++) {
      float4 a = *(const float4*)&As[r0 + i][k];
      float t0 = acc[i][0], t1 = acc[i][1], t2 = acc[i][2], t3 = acc[i][3];
      t0 = fmaf(a.x, w0.x, t0); t1 = fmaf(a.x, w0.y, t1); t2 = fmaf(a.x, w0.z, t2); t3 = fmaf(a.x, w0.w, t3);
      t0 = fmaf(a.y, w1.x, t0); t1 = fmaf(a.y, w1.y, t1); t2 = fmaf(a.y, w1.z, t2); t3 = fmaf(a.y, w1.w, t3);
      t0 = fmaf(a.z, w2.x, t0); t1 = fmaf(a.z, w2.y, t1); t2 = fmaf(a.z, w2.z, t2); t3 = fmaf(a.z, w2.w, t3);
      t0 = fmaf(a.w, w3.x, t0); t1 = fmaf(a.w, w3.y, t1); t2 = fmaf(a.w, w3.z, t2); t3 = fmaf(a.w, w3.w, t3);
      acc[i][0] = t0; acc[i][1] = t1; acc[i][2] = t2; acc[i][3] = t3;
    }
  }
  float4 b = *(const float4*)(bias + c0);
#pragma unroll
  for (int i = 0; i < 8; i++) {
    int row = rb + r0 + i;
    if (row < nrows) {
      float4 o;
      o.x = acc[i][0] + b.x; o.y = acc[i][1] + b.y;
      o.z = acc[i][2] + b.z; o.w = acc[i][3] + b.w;
      if (ACT == 1) {
        o.x = fmaxf(o.x, 0.f); o.y = fmaxf(o.y, 0.f);
        o.z = fmaxf(o.z, 0.f); o.w = fmaxf(o.w, 0.f);
      } else if (ACT == 2) {
        o.x = fast_tanh(o.x); o.y = fast_tanh(o.y);
        o.z = fast_tanh(o.z); o.w = fast_tanh(o.w);
      }
      *(float4*)(out + (size_t)row * ldout + c0) = o;
    }
  }
}

// fused attention score: scores[row] = tanh(A[row]@W + b1) . w2 + b2
__global__ __launch_bounds__(256) void k_att(const float* __restrict__ A,
                                             const float* __restrict__ W,
                                             const float* __restrict__ bias,
                                             const float* __restrict__ w2v,
                                             const float* __restrict__ b2,
                                             float* __restrict__ scores, int nrows) {
  __shared__ float As[64][128];
  const int tid = threadIdx.x;
  const int rb = blockIdx.x * 64;
  for (int idx = tid; idx < 64 * 32; idx += 256) {
    int r = idx / 32, k4 = idx % 32;
    int row = rb + r;
    float4 v = make_float4(0.f, 0.f, 0.f, 0.f);
    if (row < nrows) v = ((const float4*)(A + (size_t)row * 128))[k4];
    ((float4*)&As[r][0])[k4] = v;
  }
  __syncthreads();
  const int cg = tid & 31, rg = tid >> 5;
  const int c0 = cg * 4;
  const int r0 = rg * 8;
  float acc[8][4];
#pragma unroll
  for (int i = 0; i < 8; i++)
#pragma unroll
    for (int j = 0; j < 4; j++) acc[i][j] = 0.f;

  for (int k = 0; k < 128; k += 4) {
    float4 w0 = *(const float4*)(W + (size_t)(k + 0) * 128 + c0);
    float4 w1 = *(const float4*)(W + (size_t)(k + 1) * 128 + c0);
    float4 w2 = *(const float4*)(W + (size_t)(k + 2) * 128 + c0);
    float4 w3 = *(const float4*)(W + (size_t)(k + 3) * 128 + c0);
#pragma unroll
    for (int i = 0; i < 8; i++) {
      float4 a = *(const float4*)&As[r0 + i][k];
      float t0 = acc[i][0], t1 = acc[i][1], t2 = acc[i][2], t3 = acc[i][3];
      t0 = fmaf(a.x, w0.x, t0); t1 = fmaf(a.x, w0.y, t1); t2 = fmaf(a.x, w0.z, t2); t3 = fmaf(a.x, w0.w, t3);
      t0 = fmaf(a.y, w1.x, t0); t1 = fmaf(a.y, w1.y, t1); t2 = fmaf(a.y, w1.z, t2); t3 = fmaf(a.y, w1.w, t3);
      t0 = fmaf(a.z, w2.x, t0); t1 = fmaf(a.z, w2.y, t1); t2 = fmaf(a.z, w2.z, t2); t3 = fmaf(a.z, w2.w, t3);
      t0 = fmaf(a.w, w3.x, t0); t1 = fmaf(a.w, w3.y, t1); t2 = fmaf(a.w, w3.z, t2); t3 = fmaf(a.w, w3.w, t3);
      acc[i][0] = t0; acc[i][1] = t1; acc[i][2] = t2; acc[i][3] = t3;
    }
  }
  float4 b = *(const float4*)(bias + c0);
  float4 wv = *(const float4*)(w2v + c0);
  float p[8];
#pragma unroll
  for (int i = 0; i < 8; i++) {
    float x0 = fast_tanh(acc[i][0] + b.x);
    float x1 = fast_tanh(acc[i][1] + b.y);
    float x2 = fast_tanh(acc[i][2] + b.z);
    float x3 = fast_tanh(acc[i][3] + b.w);
    p[i] = x0 * wv.x + x1 * wv.y + x2 * wv.z + x3 * wv.w;
  }
#pragma unroll
  for (int m = 1; m <= 16; m <<= 1)
#pragma unroll
    for (int i = 0; i < 8; i++) p[i] += __shfl_xor(p[i], m);
  if (cg == 0) {
#pragma unroll
    for (int i = 0; i < 8; i++) {
      int row = rb + r0 + i;
      if (row < nrows) scores[row] = p[i] + b2[0];
    }
  }
}

__global__ void k_softmax(const float* __restrict__ sc, float* __restrict__ aw) {
  int bn = blockIdx.x * 256 + threadIdx.x;
  if (bn >= BN_) return;
  float v[T_];
  float m = -1e30f;
#pragma unroll
  for (int t = 0; t < T_; t++) { v[t] = sc[t * BN_ + bn]; m = fmaxf(m, v[t]); }
  float s = 0.f;
#pragma unroll
  for (int t = 0; t < T_; t++) { v[t] = __expf(v[t] - m); s += v[t]; }
  float inv = __builtin_amdgcn_rcpf(s);
#pragma unroll
  for (int t = 0; t < T_; t++) aw[t * BN_ + bn] = v[t] * inv;
}

__global__ void k_wsum(const float* __restrict__ aw, const float* __restrict__ hs,
                       float* __restrict__ nf) {
  int idx = blockIdx.x * 256 + threadIdx.x;
  if (idx >= BN_ * H_) return;
  int bn = idx >> 7, f = idx & 127;
  float s = 0.f;
#pragma unroll
  for (int t = 0; t < T_; t++)
    s = fmaf(aw[t * BN_ + bn], hs[((size_t)t * BN_ + bn) * H_ + f], s);
  nf[idx] = s;
}

__global__ void k_gru(const float* __restrict__ gi, const float* __restrict__ bhh,
                      float* __restrict__ h) {
  int idx = blockIdx.x * 256 + threadIdx.x;
  if (idx >= BN_ * H_) return;
  int bn = idx >> 7, j = idx & 127;
  const float* g = gi + (size_t)bn * 384;
  float r = fast_sigmoid(g[j] + bhh[j]);
  float z = fast_sigmoid(g[128 + j] + bhh[128 + j]);
  float n = fast_tanh(g[256 + j] + r * bhh[256 + j]);
  h[idx] = (1.f - z) * n;  // h0 = 0
}

__global__ void k_postk(const float* __restrict__ kk, float* __restrict__ h,
                        float* __restrict__ acc, float* __restrict__ u,
                        float c, int mode) {
  int i = blockIdx.x * 256 + threadIdx.x;
  if (i >= BN_ * H_) return;
  float kv = kk[i];
  if (mode == 0)      { acc[i] = kv;        u[i] = fmaf(c, kv, h[i]); }
  else if (mode == 1) { acc[i] += 2.f * kv; u[i] = fmaf(c, kv, h[i]); }
  else                { h[i] = fmaf(c, acc[i] + kv, h[i]); }
}

__global__ void k_proj(const float* __restrict__ st, const float* __restrict__ ow,
                       const float* __restrict__ ob, float* __restrict__ out, int fh) {
  int wid = (blockIdx.x * blockDim.x + threadIdx.x) >> 6;
  int lane = threadIdx.x & 63;
  if (wid >= BN_) return;
  float2 a = ((const float2*)(st + (size_t)wid * 128))[lane];
  float2 w = ((const float2*)ow)[lane];
  float s = a.x * w.x + a.y * w.y;
#pragma unroll
  for (int off = 32; off > 0; off >>= 1) s += __shfl_down(s, off);
  if (lane == 0) out[(size_t)wid * FH_ + fh] = s + ob[0];
}

extern "C" void kernel_launch(void* const* d_in, const int* in_sizes, int n_in,
                              void* d_out, int out_size, void* d_ws, size_t ws_size,
                              hipStream_t stream) {
  const float* x       = (const float*)d_in[0];
  const float* gcn_w1  = (const float*)d_in[1];
  const float* gcn_b1  = (const float*)d_in[2];
  const float* gcn_w2  = (const float*)d_in[3];
  const float* gcn_b2  = (const float*)d_in[4];
  const float* gcn_w3  = (const float*)d_in[5];
  const float* gcn_b3  = (const float*)d_in[6];
  const float* att_w1  = (const float*)d_in[7];
  const float* att_b1  = (const float*)d_in[8];
  const float* att_w2  = (const float*)d_in[9];
  const float* att_b2  = (const float*)d_in[10];
  const float* gru_wih = (const float*)d_in[11];
  const float* gru_bih = (const float*)d_in[13];
  const float* gru_bhh = (const float*)d_in[14];
  const float* ode_w1  = (const float*)d_in[15];
  const float* ode_b1  = (const float*)d_in[16];
  const float* ode_w2  = (const float*)d_in[17];
  const float* ode_b2  = (const float*)d_in[18];
  const float* out_w   = (const float*)d_in[19];
  const float* out_b   = (const float*)d_in[20];
  const int*   eidx    = (const int*)d_in[21];
  float* out = (float*)d_out;

  float* wsf = (float*)d_ws;
  size_t off = 0;
  float* h_seq = wsf + off; off += (size_t)T_ * BN_ * H_;   // also gi scratch (BN*384)
  float* W0 = wsf + off; off += (size_t)BN_ * H_;
  float* W1 = wsf + off; off += (size_t)BN_ * H_;
  float* W2 = wsf + off; off += (size_t)BN_ * H_;           // hidden / ODE state
  float* W3 = wsf + off; off += (size_t)BN_ * H_;           // u
  float* W4 = wsf + off; off += (size_t)BN_ * H_;           // k
  float* W5 = wsf + off; off += (size_t)BN_ * H_;           // acc
  float* scores = wsf + off; off += (size_t)T_ * BN_;
  float* aw = wsf + off; off += (size_t)T_ * BN_;
  float* val = wsf + off; off += TOTE_;
  float* dinv = wsf + off; off += BN_;
  float* wih_t = wsf + off; off += 384 * 128;
  int* rp  = (int*)(wsf + off); off += BN_ + 1;
  int* ci  = (int*)(wsf + off); off += TOTE_;
  int* cnt = (int*)(wsf + off); off += BN_;
  if (ws_size < off * sizeof(float)) {
    k_sentinel<<<1, 1, 0, stream>>>(out);
    return;
  }

  const int* esrc = eidx;
  const int* edst = eidx + E_;

  // ---- CSR build (per launch; deterministic up to FP summation order) ----
  k_init_cnt<<<(BN_ + 255) / 256, 256, 0, stream>>>(cnt);
  k_count<<<(E_ + 255) / 256, 256, 0, stream>>>(edst, cnt);
  k_dinv<<<(BN_ + 255) / 256, 256, 0, stream>>>(cnt, dinv);
  k_scan<<<1, 1024, 0, stream>>>(cnt, rp);
  k_fill<<<(TOTE_ + 255) / 256, 256, 0, stream>>>(esrc, edst, rp, cnt, ci, val, dinv);
  k_tw<<<(384 * 128 + 255) / 256, 256, 0, stream>>>(gru_wih, wih_t);

  const int gR = (BN_ + 63) / 64;        // 313 row-tiles
  const int gW = BN_ / 4;                // 5000 blocks, wave per row
  const int gE = (BN_ * H_ + 255) / 256; // 10000 elementwise

  // ---- spatial encoder ----
  for (int t = 0; t < T_; t++) {
    k_spmv1<<<(BN_ + 255) / 256, 256, 0, stream>>>(rp, ci, val, x, t, W0);
    k_layer1<<<(BN_ * 64 + 255) / 256, 256, 0, stream>>>(W0, gcn_w1, gcn_b1, W1);
    k_spmm<64><<<gW, 256, 0, stream>>>(rp, ci, val, W1, W0);
    k_gemm<64, 1><<<dim3(gR, 1), 256, 0, stream>>>(W0, gcn_w2, gcn_b2, W1, BN_, 128, 128);
    k_spmm<128><<<gW, 256, 0, stream>>>(rp, ci, val, W1, W0);
    k_gemm<128, 1><<<dim3(gR, 1), 256, 0, stream>>>(W0, gcn_w3, gcn_b3,
                                                    h_seq + (size_t)t * BN_ * H_, BN_, 128, 128);
  }

  // ---- temporal attention (batched over T*BN rows) ----
  k_att<<<(T_ * BN_ + 63) / 64, 256, 0, stream>>>(h_seq, att_w1, att_b1, att_w2, att_b2,
                                                  scores, T_ * BN_);
  k_softmax<<<(BN_ + 255) / 256, 256, 0, stream>>>(scores, aw);
  k_wsum<<<gE, 256, 0, stream>>>(aw, h_seq, W0);

  // ---- GRU (h0 = 0) ----
  k_gemm<128, 0><<<dim3(gR, 3), 256, 0, stream>>>(W0, wih_t, gru_bih, h_seq, BN_, 384, 384);
  k_gru<<<gE, 256, 0, stream>>>(h_seq, gru_bhh, W2);
  k_proj<<<gW, 256, 0, stream>>>(W2, out_w, out_b, out, 0);

  // ---- graph ODE, RK4 ----
  const float dt = (float)FH_ / (float)(FH_ - 1);
  auto f_eval = [&](const float* in, float* outk) {
    k_spmm<128><<<gW, 256, 0, stream>>>(rp, ci, val, in, W0);
    k_gemm<128, 2><<<dim3(gR, 1), 256, 0, stream>>>(W0, ode_w1, ode_b1, W1, BN_, 128, 128);
    k_spmm<128><<<gW, 256, 0, stream>>>(rp, ci, val, W1, W0);
    k_gemm<128, 2><<<dim3(gR, 1), 256, 0, stream>>>(W0, ode_w2, ode_b2, outk, BN_, 128, 128);
  };
  for (int s = 1; s < FH_; s++) {
    f_eval(W2, W4);
    k_postk<<<gE, 256, 0, stream>>>(W4, W2, W5, W3, 0.5f * dt, 0);
    f_eval(W3, W4);
    k_postk<<<gE, 256, 0, stream>>>(W4, W2, W5, W3, 0.5f * dt, 1);
    f_eval(W3, W4);
    k_postk<<<gE, 256, 0, stream>>>(W4, W2, W5, W3, dt, 1);
    f_eval(W3, W4);
    k_postk<<<gE, 256, 0, stream>>>(W4, W2, W5, W3, dt / 6.f, 2);
    k_proj<<<gW, 256, 0, stream>>>(W2, out_w, out_b, out, s);
  }
}

// Round 2
// 5735.971 us; speedup vs baseline: 1.2429x; 1.2429x over previous
//
#include <hip/hip_runtime.h>
#include <stdint.h>

#define B_ 4
#define N_ 5000
#define T_ 12
#define FH_ 12
#define H_ 128
#define BN_ 20000
#define E_ 320000
#define TOTE_ (E_ + BN_)

typedef __attribute__((ext_vector_type(8))) short s8v;
typedef __attribute__((ext_vector_type(4))) float f32x4;

__device__ __forceinline__ float fast_tanh(float x) {
  float e = __expf(2.f * x);
  return 1.f - 2.f * __builtin_amdgcn_rcpf(e + 1.f);
}
__device__ __forceinline__ float fast_sigmoid(float x) {
  return __builtin_amdgcn_rcpf(1.f + __expf(-x));
}
__device__ __forceinline__ unsigned short f2bf(float f) {  // RNE
  unsigned u = __float_as_uint(f);
  u = (u + 0x7fffu + ((u >> 16) & 1u)) >> 16;
  return (unsigned short)u;
}
__device__ __forceinline__ float bf2f(unsigned short u) {
  return __uint_as_float(((unsigned)u) << 16);
}

__global__ void k_sentinel(float* out) { out[0] = 1e30f; }

__global__ void k_init_cnt(int* cnt) {
  int i = blockIdx.x * 256 + threadIdx.x;
  if (i < BN_) cnt[i] = 1;  // self-loop
}
__global__ void k_count(const int* __restrict__ dst, int* cnt) {
  int e = blockIdx.x * 256 + threadIdx.x;
  if (e < E_) atomicAdd(&cnt[dst[e]], 1);
}
__global__ void k_dinv(const int* __restrict__ cnt, float* __restrict__ dinv) {
  int i = blockIdx.x * 256 + threadIdx.x;
  if (i < BN_) dinv[i] = rsqrtf((float)cnt[i]);
}
__global__ void k_scan(int* cnt, int* rp) {
  __shared__ int sh[1024];
  int tid = threadIdx.x;
  const int per = (BN_ + 1023) / 1024;
  int start = tid * per;
  int end = start + per; if (end > BN_) end = BN_;
  int s = 0;
  for (int i = start; i < end; i++) s += cnt[i];
  sh[tid] = s;
  __syncthreads();
  for (int off = 1; off < 1024; off <<= 1) {
    int v = (tid >= off) ? sh[tid - off] : 0;
    __syncthreads();
    sh[tid] += v;
    __syncthreads();
  }
  int run = (tid > 0) ? sh[tid - 1] : 0;
  for (int i = start; i < end; i++) {
    int c = cnt[i];
    rp[i] = run;
    run += c;
    cnt[i] = 0;
  }
  if (tid == 1023) rp[BN_] = sh[1023];
}
__global__ void k_fill(const int* __restrict__ src, const int* __restrict__ dst,
                       const int* __restrict__ rp, int* cnt, int* ci,
                       float* val, const float* __restrict__ dinv) {
  int e = blockIdx.x * 256 + threadIdx.x;
  if (e >= TOTE_) return;
  int s, d;
  if (e < E_) { s = src[e]; d = dst[e]; }
  else { s = d = e - E_; }
  int pos = rp[d] + atomicAdd(&cnt[d], 1);
  ci[pos] = s;
  val[pos] = dinv[s] * dinv[d];
}

// pack weight (K x Nn, k-major; or transposed source: src[n*K+k]) into MFMA B-frag layout:
// dst[((kc*NT + nt)*64 + l)*8 + j] = W[kc*32 + (l>>4)*8 + j][nt*16 + (l&15)]
__global__ void k_prep(const float* __restrict__ src, unsigned short* __restrict__ dst,
                       int K, int Nn, int transposed) {
  int idx = blockIdx.x * 256 + threadIdx.x;
  if (idx >= K * Nn) return;
  int j = idx & 7, l = (idx >> 3) & 63, rest = idx >> 9;
  int NT = Nn >> 4;
  int nt = rest % NT, kc = rest / NT;
  int k = kc * 32 + ((l >> 4) << 3) + j;
  int n = nt * 16 + (l & 15);
  float v = transposed ? src[n * K + k] : src[k * Nn + n];
  dst[idx] = f2bf(v);
}

// fused: agg = S*x_t (scalar per row), then h1 = relu(agg*w1 + b1)  -> bf16 (BN x 64)
__global__ void k_spl1(const int* __restrict__ rp, const int* __restrict__ ci,
                       const float* __restrict__ val, const float* __restrict__ x, int t,
                       const float* __restrict__ w1, const float* __restrict__ b1,
                       unsigned short* __restrict__ h1) {
  int wid = (blockIdx.x * 256 + threadIdx.x) >> 6;
  int lane = threadIdx.x & 63;
  if (wid >= BN_) return;
  int beg = rp[wid], end = rp[wid + 1];
  float a = 0.f;
  for (int e = beg + lane; e < end; e += 64)
    a = fmaf(val[e], x[(size_t)ci[e] * T_ + t], a);
#pragma unroll
  for (int m = 1; m < 64; m <<= 1) a += __shfl_xor(a, m);
  float v = fmaf(a, w1[lane], b1[lane]);
  h1[(size_t)wid * 64 + lane] = f2bf(fmaxf(v, 0.f));
}

// bf16 SpMM: out[r,:] = sum_e val[e] * in[ci[e],:]   (WE = 64 or 128 wide)
template<int WE>
__global__ void k_spmmb(const int* __restrict__ rp, const int* __restrict__ ci,
                        const float* __restrict__ val, const unsigned short* __restrict__ in,
                        unsigned short* __restrict__ out) {
  int wid = (blockIdx.x * 256 + threadIdx.x) >> 6;
  int lane = threadIdx.x & 63;
  if (wid >= BN_) return;
  int beg = rp[wid], end = rp[wid + 1];
  if (WE == 128) {
    float a0 = 0.f, a1 = 0.f;
    for (int e = beg; e < end; e++) {
      int s = ci[e]; float v = val[e];
      unsigned p = *(const unsigned*)(in + (size_t)s * 128 + lane * 2);
      a0 = fmaf(v, bf2f((unsigned short)(p & 0xffffu)), a0);
      a1 = fmaf(v, bf2f((unsigned short)(p >> 16)), a1);
    }
    unsigned o = ((unsigned)f2bf(a1) << 16) | f2bf(a0);
    *(unsigned*)(out + (size_t)wid * 128 + lane * 2) = o;
  } else {
    float a = 0.f;
    for (int e = beg; e < end; e++)
      a = fmaf(val[e], bf2f(in[(size_t)ci[e] * 64 + lane]), a);
    out[(size_t)wid * 64 + lane] = f2bf(a);
  }
}

// MFMA GEMM: block = 64 rows x 128 cols, 4 waves, wave = 16 rows x 128 cols.
// A: bf16 row-major [nrows x K]. Wf: frag-packed bf16. grid.y selects 128-col panel.
// act: 0 none, 1 relu, 2 tanh.
// mode: 0 plain store (outb bf16 and/or outf fp32);
//       1 k1: rkacc=kv, u=h+c1*kv; 2 k2/k3: rkacc+=2kv, u=h+c1*kv;
//       3 k4: h+=c2*(rkacc+kv), ubf=bf16(h);
//       4 att: scores[row] = sum_col tanh(d+bias)*w2v[col] + b2
template<int KC>
__global__ __launch_bounds__(256) void k_mgemm(
    const unsigned short* __restrict__ A, const unsigned short* __restrict__ Wf,
    const float* __restrict__ bias, int nrows, int NTt,
    int act, int mode, float c1, float c2,
    unsigned short* __restrict__ outb, float* __restrict__ outf, int ldout,
    float* __restrict__ h, float* __restrict__ rkacc, unsigned short* __restrict__ ubf,
    const float* __restrict__ w2v, const float* __restrict__ b2,
    float* __restrict__ scores) {
  const int tid = threadIdx.x;
  const int l = tid & 63;
  const int w = tid >> 6;
  const int m0 = blockIdx.x * 64 + w * 16;
  const int cb = blockIdx.y * 128;
  const int ntg0 = blockIdx.y * 8;
  const int K = KC * 32;

  f32x4 acc[8];
#pragma unroll
  for (int nt = 0; nt < 8; nt++) acc[nt] = (f32x4){0.f, 0.f, 0.f, 0.f};

  int arow = m0 + (l & 15);
  if (arow >= nrows) arow = nrows - 1;
  const unsigned short* Ap = A + (size_t)arow * K + ((l >> 4) << 3);

#pragma unroll
  for (int kc = 0; kc < KC; kc++) {
    s8v av = *(const s8v*)(Ap + kc * 32);
#pragma unroll
    for (int nt = 0; nt < 8; nt++) {
      const unsigned short* bp = Wf + (((size_t)((kc * NTt) + ntg0 + nt)) << 9) + (l << 3);
      s8v bv = *(const s8v*)bp;
      acc[nt] = __builtin_amdgcn_mfma_f32_16x16x32_bf16(av, bv, acc[nt], 0, 0, 0);
    }
  }

  if (mode == 4) {
    float p[4] = {0.f, 0.f, 0.f, 0.f};
#pragma unroll
    for (int nt = 0; nt < 8; nt++) {
      int col = nt * 16 + (l & 15);
      float bi = bias[col], wv = w2v[col];
#pragma unroll
      for (int reg = 0; reg < 4; reg++)
        p[reg] = fmaf(fast_tanh(acc[nt][reg] + bi), wv, p[reg]);
    }
#pragma unroll
    for (int m = 1; m <= 8; m <<= 1)
#pragma unroll
      for (int reg = 0; reg < 4; reg++) p[reg] += __shfl_xor(p[reg], m);
    if ((l & 15) == 0) {
      float bb = b2[0];
#pragma unroll
      for (int reg = 0; reg < 4; reg++) {
        int row = m0 + ((l >> 4) << 2) + reg;
        if (row < nrows) scores[row] = p[reg] + bb;
      }
    }
    return;
  }

#pragma unroll
  for (int nt = 0; nt < 8; nt++) {
    int col = cb + nt * 16 + (l & 15);
    float bi = bias[col];
#pragma unroll
    for (int reg = 0; reg < 4; reg++) {
      int row = m0 + ((l >> 4) << 2) + reg;
      if (row >= nrows) continue;
      float v = acc[nt][reg] + bi;
      if (act == 1) v = fmaxf(v, 0.f);
      else if (act == 2) v = fast_tanh(v);
      size_t oi = (size_t)row * ldout + col;
      if (mode == 0) {
        if (outb) outb[oi] = f2bf(v);
        if (outf) outf[oi] = v;
      } else if (mode == 1) {
        float hv = h[oi];
        rkacc[oi] = v;
        ubf[oi] = f2bf(fmaf(c1, v, hv));
      } else if (mode == 2) {
        float hv = h[oi];
        rkacc[oi] += 2.f * v;
        ubf[oi] = f2bf(fmaf(c1, v, hv));
      } else {  // mode 3
        float nh = fmaf(c2, rkacc[oi] + v, h[oi]);
        h[oi] = nh;
        ubf[oi] = f2bf(nh);
      }
    }
  }
}

__global__ void k_softmax(const float* __restrict__ sc, float* __restrict__ aw) {
  int bn = blockIdx.x * 256 + threadIdx.x;
  if (bn >= BN_) return;
  float v[T_];
  float m = -1e30f;
#pragma unroll
  for (int t = 0; t < T_; t++) { v[t] = sc[t * BN_ + bn]; m = fmaxf(m, v[t]); }
  float s = 0.f;
#pragma unroll
  for (int t = 0; t < T_; t++) { v[t] = __expf(v[t] - m); s += v[t]; }
  float inv = __builtin_amdgcn_rcpf(s);
#pragma unroll
  for (int t = 0; t < T_; t++) aw[t * BN_ + bn] = v[t] * inv;
}

__global__ void k_wsum(const float* __restrict__ aw, const unsigned short* __restrict__ hs,
                       unsigned short* __restrict__ nf) {
  int idx = blockIdx.x * 256 + threadIdx.x;
  if (idx >= BN_ * H_) return;
  int bn = idx >> 7, f = idx & 127;
  float s = 0.f;
#pragma unroll
  for (int t = 0; t < T_; t++)
    s = fmaf(aw[t * BN_ + bn], bf2f(hs[((size_t)t * BN_ + bn) * H_ + f]), s);
  nf[idx] = f2bf(s);
}

__global__ void k_gru(const float* __restrict__ gi, const float* __restrict__ bhh,
                      float* __restrict__ h, unsigned short* __restrict__ hbf) {
  int idx = blockIdx.x * 256 + threadIdx.x;
  if (idx >= BN_ * H_) return;
  int bn = idx >> 7, j = idx & 127;
  const float* g = gi + (size_t)bn * 384;
  float r = fast_sigmoid(g[j] + bhh[j]);
  float z = fast_sigmoid(g[128 + j] + bhh[128 + j]);
  float n = fast_tanh(g[256 + j] + r * bhh[256 + j]);
  float hv = (1.f - z) * n;  // h0 = 0
  h[idx] = hv;
  hbf[idx] = f2bf(hv);
}

__global__ void k_proj(const float* __restrict__ st, const float* __restrict__ ow,
                       const float* __restrict__ ob, float* __restrict__ out, int fh) {
  int wid = (blockIdx.x * blockDim.x + threadIdx.x) >> 6;
  int lane = threadIdx.x & 63;
  if (wid >= BN_) return;
  float2 a = ((const float2*)(st + (size_t)wid * 128))[lane];
  float2 w = ((const float2*)ow)[lane];
  float s = a.x * w.x + a.y * w.y;
#pragma unroll
  for (int off = 32; off > 0; off >>= 1) s += __shfl_down(s, off);
  if (lane == 0) out[(size_t)wid * FH_ + fh] = s + ob[0];
}

extern "C" void kernel_launch(void* const* d_in, const int* in_sizes, int n_in,
                              void* d_out, int out_size, void* d_ws, size_t ws_size,
                              hipStream_t stream) {
  const float* x       = (const float*)d_in[0];
  const float* gcn_w1  = (const float*)d_in[1];
  const float* gcn_b1  = (const float*)d_in[2];
  const float* gcn_w2  = (const float*)d_in[3];
  const float* gcn_b2  = (const float*)d_in[4];
  const float* gcn_w3  = (const float*)d_in[5];
  const float* gcn_b3  = (const float*)d_in[6];
  const float* att_w1  = (const float*)d_in[7];
  const float* att_b1  = (const float*)d_in[8];
  const float* att_w2  = (const float*)d_in[9];
  const float* att_b2  = (const float*)d_in[10];
  const float* gru_wih = (const float*)d_in[11];
  const float* gru_bih = (const float*)d_in[13];
  const float* gru_bhh = (const float*)d_in[14];
  const float* ode_w1  = (const float*)d_in[15];
  const float* ode_b1  = (const float*)d_in[16];
  const float* ode_w2  = (const float*)d_in[17];
  const float* ode_b2  = (const float*)d_in[18];
  const float* out_w   = (const float*)d_in[19];
  const float* out_b   = (const float*)d_in[20];
  const int*   eidx    = (const int*)d_in[21];
  float* out = (float*)d_out;

  float* wsf = (float*)d_ws;
  size_t off = 0;
  float* gi     = wsf + off; off += (size_t)BN_ * 384;
  float* hst    = wsf + off; off += (size_t)BN_ * H_;   // fp32 ODE state
  float* rkacc  = wsf + off; off += (size_t)BN_ * H_;
  float* scores = wsf + off; off += (size_t)T_ * BN_;
  float* aw     = wsf + off; off += (size_t)T_ * BN_;
  float* val    = wsf + off; off += TOTE_;
  float* dinv   = wsf + off; off += BN_;
  unsigned short* hseqb = (unsigned short*)(wsf + off); off += (size_t)T_ * BN_ * H_ / 2;
  unsigned short* hbf   = (unsigned short*)(wsf + off); off += (size_t)BN_ * H_ / 2;
  unsigned short* ubf   = (unsigned short*)(wsf + off); off += (size_t)BN_ * H_ / 2;
  unsigned short* t1bf  = (unsigned short*)(wsf + off); off += (size_t)BN_ * H_ / 2;
  unsigned short* aggbf = (unsigned short*)(wsf + off); off += (size_t)BN_ * H_ / 2;
  unsigned short* h1bf  = (unsigned short*)(wsf + off); off += (size_t)BN_ * 64 / 2;
  unsigned short* ag64  = (unsigned short*)(wsf + off); off += (size_t)BN_ * 64 / 2;
  unsigned short* nfbf  = (unsigned short*)(wsf + off); off += (size_t)BN_ * H_ / 2;
  unsigned short* w2f   = (unsigned short*)(wsf + off); off += 64 * 128 / 2;
  unsigned short* w3f   = (unsigned short*)(wsf + off); off += 128 * 128 / 2;
  unsigned short* aw1f  = (unsigned short*)(wsf + off); off += 128 * 128 / 2;
  unsigned short* ow1f  = (unsigned short*)(wsf + off); off += 128 * 128 / 2;
  unsigned short* ow2f  = (unsigned short*)(wsf + off); off += 128 * 128 / 2;
  unsigned short* wihf  = (unsigned short*)(wsf + off); off += 128 * 384 / 2;
  int* rp  = (int*)(wsf + off); off += BN_ + 1;
  int* ci  = (int*)(wsf + off); off += TOTE_;
  int* cnt = (int*)(wsf + off); off += BN_;
  if (ws_size < off * sizeof(float)) {
    k_sentinel<<<1, 1, 0, stream>>>(out);
    return;
  }

  const int* esrc = eidx;
  const int* edst = eidx + E_;

  // ---- CSR build + weight prep ----
  k_init_cnt<<<(BN_ + 255) / 256, 256, 0, stream>>>(cnt);
  k_count<<<(E_ + 255) / 256, 256, 0, stream>>>(edst, cnt);
  k_dinv<<<(BN_ + 255) / 256, 256, 0, stream>>>(cnt, dinv);
  k_scan<<<1, 1024, 0, stream>>>(cnt, rp);
  k_fill<<<(TOTE_ + 255) / 256, 256, 0, stream>>>(esrc, edst, rp, cnt, ci, val, dinv);
  k_prep<<<(64 * 128 + 255) / 256, 256, 0, stream>>>(gcn_w2, w2f, 64, 128, 0);
  k_prep<<<(128 * 128 + 255) / 256, 256, 0, stream>>>(gcn_w3, w3f, 128, 128, 0);
  k_prep<<<(128 * 128 + 255) / 256, 256, 0, stream>>>(att_w1, aw1f, 128, 128, 0);
  k_prep<<<(128 * 128 + 255) / 256, 256, 0, stream>>>(ode_w1, ow1f, 128, 128, 0);
  k_prep<<<(128 * 128 + 255) / 256, 256, 0, stream>>>(ode_w2, ow2f, 128, 128, 0);
  k_prep<<<(128 * 384 + 255) / 256, 256, 0, stream>>>(gru_wih, wihf, 128, 384, 1);

  const int gW = BN_ / 4;                       // wave-per-row kernels
  const int gR = (BN_ + 63) / 64;               // 313 MFMA row-tiles
  const int gE = (BN_ * H_ + 255) / 256;

  // ---- spatial encoder ----
  for (int t = 0; t < T_; t++) {
    k_spl1<<<gW, 256, 0, stream>>>(rp, ci, val, x, t, gcn_w1, gcn_b1, h1bf);
    k_spmmb<64><<<gW, 256, 0, stream>>>(rp, ci, val, h1bf, ag64);
    k_mgemm<2><<<dim3(gR, 1), 256, 0, stream>>>(ag64, w2f, gcn_b2, BN_, 8, 1, 0, 0.f, 0.f,
                                                t1bf, nullptr, 128, nullptr, nullptr, nullptr,
                                                nullptr, nullptr, nullptr);
    k_spmmb<128><<<gW, 256, 0, stream>>>(rp, ci, val, t1bf, aggbf);
    k_mgemm<4><<<dim3(gR, 1), 256, 0, stream>>>(aggbf, w3f, gcn_b3, BN_, 8, 1, 0, 0.f, 0.f,
                                                hseqb + (size_t)t * BN_ * H_, nullptr, 128,
                                                nullptr, nullptr, nullptr, nullptr, nullptr, nullptr);
  }

  // ---- temporal attention ----
  k_mgemm<4><<<dim3((T_ * BN_ + 63) / 64, 1), 256, 0, stream>>>(
      hseqb, aw1f, att_b1, T_ * BN_, 8, 2, 4, 0.f, 0.f,
      nullptr, nullptr, 128, nullptr, nullptr, nullptr, att_w2, att_b2, scores);
  k_softmax<<<(BN_ + 255) / 256, 256, 0, stream>>>(scores, aw);
  k_wsum<<<gE, 256, 0, stream>>>(aw, hseqb, nfbf);

  // ---- GRU ----
  k_mgemm<4><<<dim3(gR, 3), 256, 0, stream>>>(nfbf, wihf, gru_bih, BN_, 24, 0, 0, 0.f, 0.f,
                                              nullptr, gi, 384, nullptr, nullptr, nullptr,
                                              nullptr, nullptr, nullptr);
  k_gru<<<gE, 256, 0, stream>>>(gi, gru_bhh, hst, hbf);
  k_proj<<<gW, 256, 0, stream>>>(hst, out_w, out_b, out, 0);

  // ---- graph ODE, RK4 with fused state updates ----
  const float dt = (float)FH_ / (float)(FH_ - 1);
  auto f_eval = [&](const unsigned short* inbf, int mode, float c1, float c2,
                    unsigned short* ub) {
    k_spmmb<128><<<gW, 256, 0, stream>>>(rp, ci, val, inbf, aggbf);
    k_mgemm<4><<<dim3(gR, 1), 256, 0, stream>>>(aggbf, ow1f, ode_b1, BN_, 8, 2, 0, 0.f, 0.f,
                                                t1bf, nullptr, 128, nullptr, nullptr, nullptr,
                                                nullptr, nullptr, nullptr);
    k_spmmb<128><<<gW, 256, 0, stream>>>(rp, ci, val, t1bf, aggbf);
    k_mgemm<4><<<dim3(gR, 1), 256, 0, stream>>>(aggbf, ow2f, ode_b2, BN_, 8, 2, mode, c1, c2,
                                                nullptr, nullptr, 128, hst, rkacc, ub,
                                                nullptr, nullptr, nullptr);
  };
  for (int s = 1; s < FH_; s++) {
    f_eval(hbf, 1, 0.5f * dt, 0.f, ubf);
    f_eval(ubf, 2, 0.5f * dt, 0.f, ubf);
    f_eval(ubf, 2, dt, 0.f, ubf);
    f_eval(ubf, 3, 0.f, dt / 6.f, hbf);
    k_proj<<<gW, 256, 0, stream>>>(hst, out_w, out_b, out, s);
  }
}

// Round 3
// 4294.779 us; speedup vs baseline: 1.6600x; 1.3356x over previous
//
#include <hip/hip_runtime.h>
#include <stdint.h>

#define B_ 4
#define N_ 5000
#define T_ 12
#define FH_ 12
#define H_ 128
#define BN_ 20000
#define E_ 320000
#define TOTE_ (E_ + BN_)

typedef __attribute__((ext_vector_type(8))) short s8v;
typedef __attribute__((ext_vector_type(4))) float f32x4;

__device__ __forceinline__ float fast_tanh(float x) {
  float e = __expf(2.f * x);
  return 1.f - 2.f * __builtin_amdgcn_rcpf(e + 1.f);
}
__device__ __forceinline__ float fast_sigmoid(float x) {
  return __builtin_amdgcn_rcpf(1.f + __expf(-x));
}
__device__ __forceinline__ unsigned short f2bf(float f) {  // RNE
  unsigned u = __float_as_uint(f);
  u = (u + 0x7fffu + ((u >> 16) & 1u)) >> 16;
  return (unsigned short)u;
}
__device__ __forceinline__ float bf2f(unsigned short u) {
  return __uint_as_float(((unsigned)u) << 16);
}

__global__ void k_sentinel(float* out) { out[0] = 1e30f; }

__global__ void k_init_cnt(int* cnt) {
  int i = blockIdx.x * 256 + threadIdx.x;
  if (i < BN_) cnt[i] = 1;  // self-loop
}
__global__ void k_count(const int* __restrict__ dst, int* cnt) {
  int e = blockIdx.x * 256 + threadIdx.x;
  if (e < E_) atomicAdd(&cnt[dst[e]], 1);
}
__global__ void k_dinv(const int* __restrict__ cnt, float* __restrict__ dinv) {
  int i = blockIdx.x * 256 + threadIdx.x;
  if (i < BN_) dinv[i] = rsqrtf((float)cnt[i]);
}
__global__ void k_scan(int* cnt, int* rp) {
  __shared__ int sh[1024];
  int tid = threadIdx.x;
  const int per = (BN_ + 1023) / 1024;
  int start = tid * per;
  int end = start + per; if (end > BN_) end = BN_;
  int s = 0;
  for (int i = start; i < end; i++) s += cnt[i];
  sh[tid] = s;
  __syncthreads();
  for (int off = 1; off < 1024; off <<= 1) {
    int v = (tid >= off) ? sh[tid - off] : 0;
    __syncthreads();
    sh[tid] += v;
    __syncthreads();
  }
  int run = (tid > 0) ? sh[tid - 1] : 0;
  for (int i = start; i < end; i++) {
    int c = cnt[i];
    rp[i] = run;
    run += c;
    cnt[i] = 0;
  }
  if (tid == 1023) rp[BN_] = sh[1023];
}
__global__ void k_fill(const int* __restrict__ src, const int* __restrict__ dst,
                       const int* __restrict__ rp, int* cnt, int* ci,
                       float* val, const float* __restrict__ dinv) {
  int e = blockIdx.x * 256 + threadIdx.x;
  if (e >= TOTE_) return;
  int s, d;
  if (e < E_) { s = src[e]; d = dst[e]; }
  else { s = d = e - E_; }
  int pos = rp[d] + atomicAdd(&cnt[d], 1);
  ci[pos] = s;
  val[pos] = dinv[s] * dinv[d];
}

// pack weight into MFMA B-frag layout:
// dst[((kc*NT + nt)*64 + l)*8 + j] = W[kc*32 + (l>>4)*8 + j][nt*16 + (l&15)]
__global__ void k_prep(const float* __restrict__ src, unsigned short* __restrict__ dst,
                       int K, int Nn, int transposed) {
  int idx = blockIdx.x * 256 + threadIdx.x;
  if (idx >= K * Nn) return;
  int j = idx & 7, l = (idx >> 3) & 63, rest = idx >> 9;
  int NT = Nn >> 4;
  int nt = rest % NT, kc = rest / NT;
  int k = kc * 32 + ((l >> 4) << 3) + j;
  int n = nt * 16 + (l & 15);
  float v = transposed ? src[n * K + k] : src[k * Nn + n];
  dst[idx] = f2bf(v);
}

// fused: agg = S*x_t (scalar per row), then h1 = relu(agg*w1 + b1) -> bf16 (BN x 64)
__global__ void k_spl1(const int* __restrict__ rp, const int* __restrict__ ci,
                       const float* __restrict__ val, const float* __restrict__ x, int t,
                       const float* __restrict__ w1, const float* __restrict__ b1,
                       unsigned short* __restrict__ h1) {
  int wid = (blockIdx.x * 256 + threadIdx.x) >> 6;
  int lane = threadIdx.x & 63;
  if (wid >= BN_) return;
  int beg = rp[wid], end = rp[wid + 1];
  float a = 0.f;
  for (int e = beg + lane; e < end; e += 64)
    a = fmaf(val[e], x[(size_t)ci[e] * T_ + t], a);
#pragma unroll
  for (int m = 1; m < 64; m <<= 1) a += __shfl_xor(a, m);
  float v = fmaf(a, w1[lane], b1[lane]);
  h1[(size_t)wid * 64 + lane] = f2bf(fmaxf(v, 0.f));
}

// ---------------- fused SpMM + MFMA GEMM + epilogue ----------------
// grid = 640 blocks x 256 thr. XCD-swizzled: xcd=bid&7 owns batch xcd>>1.
// Block handles 32 rows of one batch. Gather into padded LDS, then 2 waves
// do MFMA (wave w: rows w*16..w*16+15 x all 128 cols) + epilogue.
// act: 0 none, 1 relu, 2 tanh
// mode 0: outb[row*128+col] = bf16(v)
// mode 1: rkacc=v, ubf=bf16(h+c1*v)
// mode 2: rkacc+=2v, ubf=bf16(h+c1*v)
// mode 3: h+=c2*(rkacc+v), ubf=bf16(h), outp[row*FH+step]=dot(h_row,ow)+ob
template<int KIN>
__global__ __launch_bounds__(256) void k_fused(
    const int* __restrict__ rp, const int* __restrict__ ci, const float* __restrict__ val,
    const unsigned short* __restrict__ in,
    const unsigned short* __restrict__ Wf, const float* __restrict__ bias,
    int act, int mode, float c1, float c2,
    unsigned short* __restrict__ outb,
    float* __restrict__ h, float* __restrict__ rkacc, unsigned short* __restrict__ ubf,
    const float* __restrict__ ow, const float* __restrict__ ob,
    float* __restrict__ outp, int step) {
  constexpr int KC = KIN / 32;
  constexpr int LDK = KIN + 8;  // +16B pad: A-frag ds_read_b128 2-way (free)
  __shared__ unsigned short agg[32][LDK];
  const int tid = threadIdx.x;
  const int l = tid & 63;
  const int w = tid >> 6;
  const int bid = blockIdx.x;
  const int xcd = bid & 7, slot = bid >> 3;
  const int b = xcd >> 1;
  const int within = slot * 2 + (xcd & 1);   // 0..159
  const int wr0 = within * 32;
  const int bbase = b * N_;

  // ---- gather phase: wave w gathers local rows w*8 .. w*8+7 ----
  for (int r8 = 0; r8 < 8; r8++) {
    int lr = w * 8 + r8;
    int wr = wr0 + lr;
    if (wr >= N_) break;  // uniform across wave
    int grow = bbase + wr;
    int beg = rp[grow], end = rp[grow + 1];
    if (KIN == 128) {
      float a0 = 0.f, a1 = 0.f;
      int e = beg;
      for (; e + 3 < end; e += 4) {
        int s0 = ci[e], s1 = ci[e + 1], s2 = ci[e + 2], s3 = ci[e + 3];
        float v0 = val[e], v1 = val[e + 1], v2 = val[e + 2], v3 = val[e + 3];
        unsigned p0 = *(const unsigned*)(in + (size_t)s0 * 128 + l * 2);
        unsigned p1 = *(const unsigned*)(in + (size_t)s1 * 128 + l * 2);
        unsigned p2 = *(const unsigned*)(in + (size_t)s2 * 128 + l * 2);
        unsigned p3 = *(const unsigned*)(in + (size_t)s3 * 128 + l * 2);
        a0 = fmaf(v0, bf2f((unsigned short)(p0 & 0xffffu)), a0);
        a1 = fmaf(v0, bf2f((unsigned short)(p0 >> 16)), a1);
        a0 = fmaf(v1, bf2f((unsigned short)(p1 & 0xffffu)), a0);
        a1 = fmaf(v1, bf2f((unsigned short)(p1 >> 16)), a1);
        a0 = fmaf(v2, bf2f((unsigned short)(p2 & 0xffffu)), a0);
        a1 = fmaf(v2, bf2f((unsigned short)(p2 >> 16)), a1);
        a0 = fmaf(v3, bf2f((unsigned short)(p3 & 0xffffu)), a0);
        a1 = fmaf(v3, bf2f((unsigned short)(p3 >> 16)), a1);
      }
      for (; e < end; e++) {
        int s = ci[e]; float v = val[e];
        unsigned p = *(const unsigned*)(in + (size_t)s * 128 + l * 2);
        a0 = fmaf(v, bf2f((unsigned short)(p & 0xffffu)), a0);
        a1 = fmaf(v, bf2f((unsigned short)(p >> 16)), a1);
      }
      unsigned o = ((unsigned)f2bf(a1) << 16) | f2bf(a0);
      *(unsigned*)&agg[lr][l * 2] = o;
    } else {
      float a = 0.f;
      int e = beg;
      for (; e + 3 < end; e += 4) {
        int s0 = ci[e], s1 = ci[e + 1], s2 = ci[e + 2], s3 = ci[e + 3];
        float v0 = val[e], v1 = val[e + 1], v2 = val[e + 2], v3 = val[e + 3];
        unsigned short q0 = in[(size_t)s0 * 64 + l];
        unsigned short q1 = in[(size_t)s1 * 64 + l];
        unsigned short q2 = in[(size_t)s2 * 64 + l];
        unsigned short q3 = in[(size_t)s3 * 64 + l];
        a = fmaf(v0, bf2f(q0), a); a = fmaf(v1, bf2f(q1), a);
        a = fmaf(v2, bf2f(q2), a); a = fmaf(v3, bf2f(q3), a);
      }
      for (; e < end; e++)
        a = fmaf(val[e], bf2f(in[(size_t)ci[e] * 64 + l]), a);
      agg[lr][l] = f2bf(a);
    }
  }
  __syncthreads();
  if (w >= 2) return;

  // ---- MFMA phase: wave w -> rows w*16..+15, cols 0..127 ----
  const int hi = l >> 4, lo16 = l & 15;
  f32x4 acc[8];
#pragma unroll
  for (int nt = 0; nt < 8; nt++) acc[nt] = (f32x4){0.f, 0.f, 0.f, 0.f};
#pragma unroll
  for (int kc = 0; kc < KC; kc++) {
    s8v av = *(const s8v*)&agg[w * 16 + lo16][kc * 32 + hi * 8];
#pragma unroll
    for (int nt = 0; nt < 8; nt++) {
      s8v bv = *(const s8v*)(Wf + (((size_t)(kc * 8 + nt)) << 9) + (l << 3));
      acc[nt] = __builtin_amdgcn_mfma_f32_16x16x32_bf16(av, bv, acc[nt], 0, 0, 0);
    }
  }

  // ---- epilogue ----
  float p[4] = {0.f, 0.f, 0.f, 0.f};
#pragma unroll
  for (int nt = 0; nt < 8; nt++) {
    int col = nt * 16 + lo16;
    float bi = bias[col];
    float owv = (mode == 3) ? ow[col] : 0.f;
#pragma unroll
    for (int reg = 0; reg < 4; reg++) {
      int lr = w * 16 + hi * 4 + reg;
      int wr = wr0 + lr;
      if (wr >= N_) continue;
      size_t oi = (size_t)(bbase + wr) * 128 + col;
      float v = acc[nt][reg] + bi;
      if (act == 1) v = fmaxf(v, 0.f);
      else if (act == 2) v = fast_tanh(v);
      if (mode == 0) {
        outb[oi] = f2bf(v);
      } else if (mode == 1) {
        float hv = h[oi];
        rkacc[oi] = v;
        ubf[oi] = f2bf(fmaf(c1, v, hv));
      } else if (mode == 2) {
        float hv = h[oi];
        rkacc[oi] += 2.f * v;
        ubf[oi] = f2bf(fmaf(c1, v, hv));
      } else {
        float nh = fmaf(c2, rkacc[oi] + v, h[oi]);
        h[oi] = nh;
        ubf[oi] = f2bf(nh);
        p[reg] = fmaf(nh, owv, p[reg]);
      }
    }
  }
  if (mode == 3) {
#pragma unroll
    for (int m = 1; m <= 8; m <<= 1)
#pragma unroll
      for (int reg = 0; reg < 4; reg++) p[reg] += __shfl_xor(p[reg], m);
    if (lo16 == 0) {
      float obv = ob[0];
#pragma unroll
      for (int reg = 0; reg < 4; reg++) {
        int wr = wr0 + w * 16 + hi * 4 + reg;
        if (wr < N_) outp[(size_t)(bbase + wr) * FH_ + step] = p[reg] + obv;
      }
    }
  }
}

// plain MFMA GEMM (attention scores mode 4, GRU mode 0 -> fp32 out)
template<int KC>
__global__ __launch_bounds__(256) void k_mgemm(
    const unsigned short* __restrict__ A, const unsigned short* __restrict__ Wf,
    const float* __restrict__ bias, int nrows, int NTt,
    int mode,
    float* __restrict__ outf, int ldout,
    const float* __restrict__ w2v, const float* __restrict__ b2,
    float* __restrict__ scores) {
  const int tid = threadIdx.x;
  const int l = tid & 63;
  const int w = tid >> 6;
  const int m0 = blockIdx.x * 64 + w * 16;
  const int cb = blockIdx.y * 128;
  const int ntg0 = blockIdx.y * 8;
  const int K = KC * 32;

  f32x4 acc[8];
#pragma unroll
  for (int nt = 0; nt < 8; nt++) acc[nt] = (f32x4){0.f, 0.f, 0.f, 0.f};

  int arow = m0 + (l & 15);
  if (arow >= nrows) arow = nrows - 1;
  const unsigned short* Ap = A + (size_t)arow * K + ((l >> 4) << 3);

#pragma unroll
  for (int kc = 0; kc < KC; kc++) {
    s8v av = *(const s8v*)(Ap + kc * 32);
#pragma unroll
    for (int nt = 0; nt < 8; nt++) {
      const unsigned short* bp = Wf + (((size_t)((kc * NTt) + ntg0 + nt)) << 9) + (l << 3);
      s8v bv = *(const s8v*)bp;
      acc[nt] = __builtin_amdgcn_mfma_f32_16x16x32_bf16(av, bv, acc[nt], 0, 0, 0);
    }
  }

  if (mode == 4) {
    float p[4] = {0.f, 0.f, 0.f, 0.f};
#pragma unroll
    for (int nt = 0; nt < 8; nt++) {
      int col = nt * 16 + (l & 15);
      float bi = bias[col], wv = w2v[col];
#pragma unroll
      for (int reg = 0; reg < 4; reg++)
        p[reg] = fmaf(fast_tanh(acc[nt][reg] + bi), wv, p[reg]);
    }
#pragma unroll
    for (int m = 1; m <= 8; m <<= 1)
#pragma unroll
      for (int reg = 0; reg < 4; reg++) p[reg] += __shfl_xor(p[reg], m);
    if ((l & 15) == 0) {
      float bb = b2[0];
#pragma unroll
      for (int reg = 0; reg < 4; reg++) {
        int row = m0 + ((l >> 4) << 2) + reg;
        if (row < nrows) scores[row] = p[reg] + bb;
      }
    }
    return;
  }

#pragma unroll
  for (int nt = 0; nt < 8; nt++) {
    int col = cb + nt * 16 + (l & 15);
    float bi = bias[col];
#pragma unroll
    for (int reg = 0; reg < 4; reg++) {
      int row = m0 + ((l >> 4) << 2) + reg;
      if (row >= nrows) continue;
      outf[(size_t)row * ldout + col] = acc[nt][reg] + bi;
    }
  }
}

__global__ void k_softmax(const float* __restrict__ sc, float* __restrict__ aw) {
  int bn = blockIdx.x * 256 + threadIdx.x;
  if (bn >= BN_) return;
  float v[T_];
  float m = -1e30f;
#pragma unroll
  for (int t = 0; t < T_; t++) { v[t] = sc[t * BN_ + bn]; m = fmaxf(m, v[t]); }
  float s = 0.f;
#pragma unroll
  for (int t = 0; t < T_; t++) { v[t] = __expf(v[t] - m); s += v[t]; }
  float inv = __builtin_amdgcn_rcpf(s);
#pragma unroll
  for (int t = 0; t < T_; t++) aw[t * BN_ + bn] = v[t] * inv;
}

__global__ void k_wsum(const float* __restrict__ aw, const unsigned short* __restrict__ hs,
                       unsigned short* __restrict__ nf) {
  int idx = blockIdx.x * 256 + threadIdx.x;
  if (idx >= BN_ * H_) return;
  int bn = idx >> 7, f = idx & 127;
  float s = 0.f;
#pragma unroll
  for (int t = 0; t < T_; t++)
    s = fmaf(aw[t * BN_ + bn], bf2f(hs[((size_t)t * BN_ + bn) * H_ + f]), s);
  nf[idx] = f2bf(s);
}

__global__ void k_gru(const float* __restrict__ gi, const float* __restrict__ bhh,
                      float* __restrict__ h, unsigned short* __restrict__ hbf) {
  int idx = blockIdx.x * 256 + threadIdx.x;
  if (idx >= BN_ * H_) return;
  int bn = idx >> 7, j = idx & 127;
  const float* g = gi + (size_t)bn * 384;
  float r = fast_sigmoid(g[j] + bhh[j]);
  float z = fast_sigmoid(g[128 + j] + bhh[128 + j]);
  float n = fast_tanh(g[256 + j] + r * bhh[256 + j]);
  float hv = (1.f - z) * n;  // h0 = 0
  h[idx] = hv;
  hbf[idx] = f2bf(hv);
}

__global__ void k_proj(const float* __restrict__ st, const float* __restrict__ ow,
                       const float* __restrict__ ob, float* __restrict__ out, int fh) {
  int wid = (blockIdx.x * blockDim.x + threadIdx.x) >> 6;
  int lane = threadIdx.x & 63;
  if (wid >= BN_) return;
  float2 a = ((const float2*)(st + (size_t)wid * 128))[lane];
  float2 w = ((const float2*)ow)[lane];
  float s = a.x * w.x + a.y * w.y;
#pragma unroll
  for (int off = 32; off > 0; off >>= 1) s += __shfl_down(s, off);
  if (lane == 0) out[(size_t)wid * FH_ + fh] = s + ob[0];
}

extern "C" void kernel_launch(void* const* d_in, const int* in_sizes, int n_in,
                              void* d_out, int out_size, void* d_ws, size_t ws_size,
                              hipStream_t stream) {
  const float* x       = (const float*)d_in[0];
  const float* gcn_w1  = (const float*)d_in[1];
  const float* gcn_b1  = (const float*)d_in[2];
  const float* gcn_w2  = (const float*)d_in[3];
  const float* gcn_b2  = (const float*)d_in[4];
  const float* gcn_w3  = (const float*)d_in[5];
  const float* gcn_b3  = (const float*)d_in[6];
  const float* att_w1  = (const float*)d_in[7];
  const float* att_b1  = (const float*)d_in[8];
  const float* att_w2  = (const float*)d_in[9];
  const float* att_b2  = (const float*)d_in[10];
  const float* gru_wih = (const float*)d_in[11];
  const float* gru_bih = (const float*)d_in[13];
  const float* gru_bhh = (const float*)d_in[14];
  const float* ode_w1  = (const float*)d_in[15];
  const float* ode_b1  = (const float*)d_in[16];
  const float* ode_w2  = (const float*)d_in[17];
  const float* ode_b2  = (const float*)d_in[18];
  const float* out_w   = (const float*)d_in[19];
  const float* out_b   = (const float*)d_in[20];
  const int*   eidx    = (const int*)d_in[21];
  float* out = (float*)d_out;

  float* wsf = (float*)d_ws;
  size_t off = 0;
  float* gi     = wsf + off; off += (size_t)BN_ * 384;
  float* hst    = wsf + off; off += (size_t)BN_ * H_;
  float* rkacc  = wsf + off; off += (size_t)BN_ * H_;
  float* scores = wsf + off; off += (size_t)T_ * BN_;
  float* aw     = wsf + off; off += (size_t)T_ * BN_;
  float* val    = wsf + off; off += TOTE_;
  float* dinv   = wsf + off; off += BN_;
  unsigned short* hseqb = (unsigned short*)(wsf + off); off += (size_t)T_ * BN_ * H_ / 2;
  unsigned short* hbf   = (unsigned short*)(wsf + off); off += (size_t)BN_ * H_ / 2;
  unsigned short* ubf   = (unsigned short*)(wsf + off); off += (size_t)BN_ * H_ / 2;
  unsigned short* t1bf  = (unsigned short*)(wsf + off); off += (size_t)BN_ * H_ / 2;
  unsigned short* h1bf  = (unsigned short*)(wsf + off); off += (size_t)BN_ * 64 / 2;
  unsigned short* nfbf  = (unsigned short*)(wsf + off); off += (size_t)BN_ * H_ / 2;
  unsigned short* w2f   = (unsigned short*)(wsf + off); off += 64 * 128 / 2;
  unsigned short* w3f   = (unsigned short*)(wsf + off); off += 128 * 128 / 2;
  unsigned short* aw1f  = (unsigned short*)(wsf + off); off += 128 * 128 / 2;
  unsigned short* ow1f  = (unsigned short*)(wsf + off); off += 128 * 128 / 2;
  unsigned short* ow2f  = (unsigned short*)(wsf + off); off += 128 * 128 / 2;
  unsigned short* wihf  = (unsigned short*)(wsf + off); off += 128 * 384 / 2;
  int* rp  = (int*)(wsf + off); off += BN_ + 1;
  int* ci  = (int*)(wsf + off); off += TOTE_;
  int* cnt = (int*)(wsf + off); off += BN_;
  if (ws_size < off * sizeof(float)) {
    k_sentinel<<<1, 1, 0, stream>>>(out);
    return;
  }

  const int* esrc = eidx;
  const int* edst = eidx + E_;

  // ---- CSR build + weight prep ----
  k_init_cnt<<<(BN_ + 255) / 256, 256, 0, stream>>>(cnt);
  k_count<<<(E_ + 255) / 256, 256, 0, stream>>>(edst, cnt);
  k_dinv<<<(BN_ + 255) / 256, 256, 0, stream>>>(cnt, dinv);
  k_scan<<<1, 1024, 0, stream>>>(cnt, rp);
  k_fill<<<(TOTE_ + 255) / 256, 256, 0, stream>>>(esrc, edst, rp, cnt, ci, val, dinv);
  k_prep<<<(64 * 128 + 255) / 256, 256, 0, stream>>>(gcn_w2, w2f, 64, 128, 0);
  k_prep<<<(128 * 128 + 255) / 256, 256, 0, stream>>>(gcn_w3, w3f, 128, 128, 0);
  k_prep<<<(128 * 128 + 255) / 256, 256, 0, stream>>>(att_w1, aw1f, 128, 128, 0);
  k_prep<<<(128 * 128 + 255) / 256, 256, 0, stream>>>(ode_w1, ow1f, 128, 128, 0);
  k_prep<<<(128 * 128 + 255) / 256, 256, 0, stream>>>(ode_w2, ow2f, 128, 128, 0);
  k_prep<<<(128 * 384 + 255) / 256, 256, 0, stream>>>(gru_wih, wihf, 128, 384, 1);

  const int gW = BN_ / 4;
  const int gR = (BN_ + 63) / 64;
  const int gE = (BN_ * H_ + 255) / 256;
  const int gF = 640;  // fused grid: 4 batches x 160 blocks, XCD-swizzled

  // ---- spatial encoder ----
  for (int t = 0; t < T_; t++) {
    k_spl1<<<gW, 256, 0, stream>>>(rp, ci, val, x, t, gcn_w1, gcn_b1, h1bf);
    k_fused<64><<<gF, 256, 0, stream>>>(rp, ci, val, h1bf, w2f, gcn_b2, 1, 0, 0.f, 0.f,
                                        t1bf, nullptr, nullptr, nullptr,
                                        nullptr, nullptr, nullptr, 0);
    k_fused<128><<<gF, 256, 0, stream>>>(rp, ci, val, t1bf, w3f, gcn_b3, 1, 0, 0.f, 0.f,
                                         hseqb + (size_t)t * BN_ * H_, nullptr, nullptr, nullptr,
                                         nullptr, nullptr, nullptr, 0);
  }

  // ---- temporal attention ----
  k_mgemm<4><<<dim3((T_ * BN_ + 63) / 64, 1), 256, 0, stream>>>(
      hseqb, aw1f, att_b1, T_ * BN_, 8, 4, nullptr, 128, att_w2, att_b2, scores);
  k_softmax<<<(BN_ + 255) / 256, 256, 0, stream>>>(scores, aw);
  k_wsum<<<gE, 256, 0, stream>>>(aw, hseqb, nfbf);

  // ---- GRU ----
  k_mgemm<4><<<dim3(gR, 3), 256, 0, stream>>>(nfbf, wihf, gru_bih, BN_, 24, 0,
                                              gi, 384, nullptr, nullptr, nullptr);
  k_gru<<<gE, 256, 0, stream>>>(gi, gru_bhh, hst, hbf);
  k_proj<<<gW, 256, 0, stream>>>(hst, out_w, out_b, out, 0);

  // ---- graph ODE, RK4: 2 fused dispatches per f-eval ----
  const float dt = (float)FH_ / (float)(FH_ - 1);
  auto f_eval = [&](const unsigned short* inbf, int mode, float c1, float c2, int step) {
    k_fused<128><<<gF, 256, 0, stream>>>(rp, ci, val, inbf, ow1f, ode_b1, 2, 0, 0.f, 0.f,
                                         t1bf, nullptr, nullptr, nullptr,
                                         nullptr, nullptr, nullptr, 0);
    k_fused<128><<<gF, 256, 0, stream>>>(rp, ci, val, t1bf, ow2f, ode_b2, 2, mode, c1, c2,
                                         nullptr, hst, rkacc, (mode == 3) ? hbf : ubf,
                                         out_w, out_b, out, step);
  };
  for (int s = 1; s < FH_; s++) {
    f_eval(hbf, 1, 0.5f * dt, 0.f, s);
    f_eval(ubf, 2, 0.5f * dt, 0.f, s);
    f_eval(ubf, 2, dt, 0.f, s);
    f_eval(ubf, 3, 0.f, dt / 6.f, s);
  }
}

// Round 4
// 2653.004 us; speedup vs baseline: 2.6873x; 1.6188x over previous
//
#include <hip/hip_runtime.h>
#include <stdint.h>

#define B_ 4
#define N_ 5000
#define T_ 12
#define FH_ 12
#define H_ 128
#define BN_ 20000
#define E_ 320000
#define TOTE_ (E_ + BN_)

typedef __attribute__((ext_vector_type(8))) short s8v;
typedef __attribute__((ext_vector_type(4))) float f32x4;

__device__ __forceinline__ float fast_tanh(float x) {
  float e = __expf(2.f * x);
  return 1.f - 2.f * __builtin_amdgcn_rcpf(e + 1.f);
}
__device__ __forceinline__ float fast_sigmoid(float x) {
  return __builtin_amdgcn_rcpf(1.f + __expf(-x));
}
__device__ __forceinline__ unsigned short f2bf(float f) {  // RNE
  unsigned u = __float_as_uint(f);
  u = (u + 0x7fffu + ((u >> 16) & 1u)) >> 16;
  return (unsigned short)u;
}
__device__ __forceinline__ float bf2f(unsigned short u) {
  return __uint_as_float(((unsigned)u) << 16);
}

__global__ void k_sentinel(float* out) { out[0] = 1e30f; }

__global__ void k_init_cnt(int* cnt) {
  int i = blockIdx.x * 256 + threadIdx.x;
  if (i < BN_) cnt[i] = 1;  // self-loop
}
__global__ void k_count(const int* __restrict__ dst, int* cnt) {
  int e = blockIdx.x * 256 + threadIdx.x;
  if (e < E_) atomicAdd(&cnt[dst[e]], 1);
}
__global__ void k_dinv(const int* __restrict__ cnt, float* __restrict__ dinv) {
  int i = blockIdx.x * 256 + threadIdx.x;
  if (i < BN_) dinv[i] = rsqrtf((float)cnt[i]);
}
__global__ void k_scan(int* cnt, int* rp) {
  __shared__ int sh[1024];
  int tid = threadIdx.x;
  const int per = (BN_ + 1023) / 1024;
  int start = tid * per;
  int end = start + per; if (end > BN_) end = BN_;
  int s = 0;
  for (int i = start; i < end; i++) s += cnt[i];
  sh[tid] = s;
  __syncthreads();
  for (int off = 1; off < 1024; off <<= 1) {
    int v = (tid >= off) ? sh[tid - off] : 0;
    __syncthreads();
    sh[tid] += v;
    __syncthreads();
  }
  int run = (tid > 0) ? sh[tid - 1] : 0;
  for (int i = start; i < end; i++) {
    int c = cnt[i];
    rp[i] = run;
    run += c;
    cnt[i] = 0;
  }
  if (tid == 1023) rp[BN_] = sh[1023];
}
// pack edges: ev[pos] = {src, bits(dinv[s]*dinv[d])}
__global__ void k_fill(const int* __restrict__ src, const int* __restrict__ dst,
                       const int* __restrict__ rp, int* cnt, int2* ev,
                       const float* __restrict__ dinv) {
  int e = blockIdx.x * 256 + threadIdx.x;
  if (e >= TOTE_) return;
  int s, d;
  if (e < E_) { s = src[e]; d = dst[e]; }
  else { s = d = e - E_; }
  int pos = rp[d] + atomicAdd(&cnt[d], 1);
  int2 p; p.x = s; p.y = __float_as_int(dinv[s] * dinv[d]);
  ev[pos] = p;
}

// pack weight into MFMA B-frag layout:
// dst[((kc*NT + nt)*64 + l)*8 + j] = W[kc*32 + (l>>4)*8 + j][nt*16 + (l&15)]
__global__ void k_prep(const float* __restrict__ src, unsigned short* __restrict__ dst,
                       int K, int Nn, int transposed) {
  int idx = blockIdx.x * 256 + threadIdx.x;
  if (idx >= K * Nn) return;
  int j = idx & 7, l = (idx >> 3) & 63, rest = idx >> 9;
  int NT = Nn >> 4;
  int nt = rest % NT, kc = rest / NT;
  int k = kc * 32 + ((l >> 4) << 3) + j;
  int n = nt * 16 + (l & 15);
  float v = transposed ? src[n * K + k] : src[k * Nn + n];
  dst[idx] = f2bf(v);
}

// fused: agg = S*x_t (scalar per row), then h1 = relu(agg*w1 + b1) -> bf16 (BN x 64)
__global__ void k_spl1(const int* __restrict__ rp, const int2* __restrict__ ev,
                       const float* __restrict__ x, int t,
                       const float* __restrict__ w1, const float* __restrict__ b1,
                       unsigned short* __restrict__ h1) {
  int wid = (blockIdx.x * 256 + threadIdx.x) >> 6;
  int lane = threadIdx.x & 63;
  if (wid >= BN_) return;
  int beg = rp[wid], end = rp[wid + 1];
  float a = 0.f;
  for (int e = beg + lane; e < end; e += 64) {
    int2 p = ev[e];
    a = fmaf(__int_as_float(p.y), x[(size_t)p.x * T_ + t], a);
  }
#pragma unroll
  for (int m = 1; m < 64; m <<= 1) a += __shfl_xor(a, m);
  float v = fmaf(a, w1[lane], b1[lane]);
  h1[(size_t)wid * 64 + lane] = f2bf(fmaxf(v, 0.f));
}

// ---------------- fused SpMM + MFMA GEMM + epilogue ----------------
// grid = 1280 x 256 thr. xcd=bid&7 owns batch xcd>>1 (L2 locality).
// Block: 16 rows. Gather: wave w rows w*4..w*4+3 -> padded LDS.
// MFMA: all 4 waves, wave w covers cols 32w..32w+31 (nt = 2w, 2w+1).
// act: 0 none, 1 relu, 2 tanh
// mode 0: outb = bf16(v)
// mode 1: rkb = bf16(v),          ubfout = bf16(bf(hbfin) + c1*v)
// mode 2: rkb = bf16(bf(rkb)+2v), ubfout = bf16(bf(hbfin) + c1*v)
// mode 3: h += c2*(bf(rkb)+v), ubfout = bf16(h), outp[row*FH+step]=dot(h,ow)+ob
template<int KIN>
__global__ __launch_bounds__(256) void k_fused(
    const int* __restrict__ rp, const int2* __restrict__ ev,
    const unsigned short* __restrict__ in,
    const unsigned short* __restrict__ Wf, const float* __restrict__ bias,
    int act, int mode, float c1, float c2,
    unsigned short* __restrict__ outb,
    const unsigned short* __restrict__ hbfin, unsigned short* __restrict__ rkb,
    float* __restrict__ h, unsigned short* __restrict__ ubfout,
    const float* __restrict__ ow, const float* __restrict__ ob,
    float* __restrict__ outp, int step) {
  constexpr int KC = KIN / 32;
  constexpr int LDK = KIN + 8;  // +16B pad: A-frag ds_read_b128 2-way (free)
  __shared__ unsigned short agg[16][LDK];
  __shared__ float ppart[4][16];
  const int tid = threadIdx.x;
  const int l = tid & 63;
  const int w = tid >> 6;
  const int bid = blockIdx.x;
  const int xcd = bid & 7, slot = bid >> 3;
  const int b = xcd >> 1;
  const int within = slot * 2 + (xcd & 1);  // 0..319
  const int wr0 = within * 16;
  const int bbase = b * N_;

  // ---- gather: wave w -> local rows w*4 .. w*4+3 ----
  for (int r4 = 0; r4 < 4; r4++) {
    int lr = w * 4 + r4;
    int wr = wr0 + lr;
    if (wr >= N_) {  // zero-fill pad rows (keep MFMA input clean)
      if (KIN == 128) *(unsigned*)&agg[lr][l * 2] = 0;
      else agg[lr][l] = 0;
      continue;
    }
    int grow = bbase + wr;
    int beg = rp[grow], end = rp[grow + 1];
    if (KIN == 128) {
      float a0 = 0.f, a1 = 0.f;
      int e = beg;
      for (; e + 3 < end; e += 4) {
        int2 e0 = ev[e], e1 = ev[e + 1], e2 = ev[e + 2], e3 = ev[e + 3];
        unsigned p0 = *(const unsigned*)(in + (size_t)e0.x * 128 + l * 2);
        unsigned p1 = *(const unsigned*)(in + (size_t)e1.x * 128 + l * 2);
        unsigned p2 = *(const unsigned*)(in + (size_t)e2.x * 128 + l * 2);
        unsigned p3 = *(const unsigned*)(in + (size_t)e3.x * 128 + l * 2);
        float v0 = __int_as_float(e0.y), v1 = __int_as_float(e1.y);
        float v2 = __int_as_float(e2.y), v3 = __int_as_float(e3.y);
        a0 = fmaf(v0, bf2f((unsigned short)(p0 & 0xffffu)), a0);
        a1 = fmaf(v0, bf2f((unsigned short)(p0 >> 16)), a1);
        a0 = fmaf(v1, bf2f((unsigned short)(p1 & 0xffffu)), a0);
        a1 = fmaf(v1, bf2f((unsigned short)(p1 >> 16)), a1);
        a0 = fmaf(v2, bf2f((unsigned short)(p2 & 0xffffu)), a0);
        a1 = fmaf(v2, bf2f((unsigned short)(p2 >> 16)), a1);
        a0 = fmaf(v3, bf2f((unsigned short)(p3 & 0xffffu)), a0);
        a1 = fmaf(v3, bf2f((unsigned short)(p3 >> 16)), a1);
      }
      for (; e < end; e++) {
        int2 e0 = ev[e];
        unsigned p = *(const unsigned*)(in + (size_t)e0.x * 128 + l * 2);
        float v = __int_as_float(e0.y);
        a0 = fmaf(v, bf2f((unsigned short)(p & 0xffffu)), a0);
        a1 = fmaf(v, bf2f((unsigned short)(p >> 16)), a1);
      }
      unsigned o = ((unsigned)f2bf(a1) << 16) | f2bf(a0);
      *(unsigned*)&agg[lr][l * 2] = o;
    } else {
      float a = 0.f;
      int e = beg;
      for (; e + 3 < end; e += 4) {
        int2 e0 = ev[e], e1 = ev[e + 1], e2 = ev[e + 2], e3 = ev[e + 3];
        unsigned short q0 = in[(size_t)e0.x * 64 + l];
        unsigned short q1 = in[(size_t)e1.x * 64 + l];
        unsigned short q2 = in[(size_t)e2.x * 64 + l];
        unsigned short q3 = in[(size_t)e3.x * 64 + l];
        a = fmaf(__int_as_float(e0.y), bf2f(q0), a);
        a = fmaf(__int_as_float(e1.y), bf2f(q1), a);
        a = fmaf(__int_as_float(e2.y), bf2f(q2), a);
        a = fmaf(__int_as_float(e3.y), bf2f(q3), a);
      }
      for (; e < end; e++) {
        int2 e0 = ev[e];
        a = fmaf(__int_as_float(e0.y), bf2f(in[(size_t)e0.x * 64 + l]), a);
      }
      agg[lr][l] = f2bf(a);
    }
  }
  __syncthreads();

  // ---- MFMA: wave w -> rows 0..15, cols 32w..32w+31 (nt = 2w, 2w+1) ----
  const int hi = l >> 4, lo16 = l & 15;
  f32x4 acc[2];
  acc[0] = (f32x4){0.f, 0.f, 0.f, 0.f};
  acc[1] = (f32x4){0.f, 0.f, 0.f, 0.f};
#pragma unroll
  for (int kc = 0; kc < KC; kc++) {
    s8v av = *(const s8v*)&agg[lo16][kc * 32 + hi * 8];
#pragma unroll
    for (int q = 0; q < 2; q++) {
      int nt = 2 * w + q;
      s8v bv = *(const s8v*)(Wf + (((size_t)(kc * 8 + nt)) << 9) + (l << 3));
      acc[q] = __builtin_amdgcn_mfma_f32_16x16x32_bf16(av, bv, acc[q], 0, 0, 0);
    }
  }

  // ---- epilogue ----
  float p[4] = {0.f, 0.f, 0.f, 0.f};
#pragma unroll
  for (int q = 0; q < 2; q++) {
    int nt = 2 * w + q;
    int col = nt * 16 + lo16;
    float bi = bias[col];
    float owv = (mode == 3) ? ow[col] : 0.f;
#pragma unroll
    for (int reg = 0; reg < 4; reg++) {
      int lr = hi * 4 + reg;
      int wr = wr0 + lr;
      if (wr >= N_) continue;
      size_t oi = (size_t)(bbase + wr) * 128 + col;
      float v = acc[q][reg] + bi;
      if (act == 1) v = fmaxf(v, 0.f);
      else if (act == 2) v = fast_tanh(v);
      if (mode == 0) {
        outb[oi] = f2bf(v);
      } else if (mode == 1) {
        float hv = bf2f(hbfin[oi]);
        rkb[oi] = f2bf(v);
        ubfout[oi] = f2bf(fmaf(c1, v, hv));
      } else if (mode == 2) {
        float hv = bf2f(hbfin[oi]);
        rkb[oi] = f2bf(bf2f(rkb[oi]) + 2.f * v);
        ubfout[oi] = f2bf(fmaf(c1, v, hv));
      } else {
        float nh = fmaf(c2, bf2f(rkb[oi]) + v, h[oi]);
        h[oi] = nh;
        ubfout[oi] = f2bf(nh);
        p[reg] = fmaf(nh, owv, p[reg]);
      }
    }
  }
  if (mode == 3) {
#pragma unroll
    for (int m = 1; m <= 8; m <<= 1)
#pragma unroll
      for (int reg = 0; reg < 4; reg++) p[reg] += __shfl_xor(p[reg], m);
    if (lo16 == 0) {
#pragma unroll
      for (int reg = 0; reg < 4; reg++) ppart[w][hi * 4 + reg] = p[reg];
    }
    __syncthreads();
    if (tid < 16) {
      int wr = wr0 + tid;
      if (wr < N_)
        outp[(size_t)(bbase + wr) * FH_ + step] =
            ppart[0][tid] + ppart[1][tid] + ppart[2][tid] + ppart[3][tid] + ob[0];
    }
  }
}

// plain MFMA GEMM (attention scores mode 4, GRU mode 0 -> fp32 out)
template<int KC>
__global__ __launch_bounds__(256) void k_mgemm(
    const unsigned short* __restrict__ A, const unsigned short* __restrict__ Wf,
    const float* __restrict__ bias, int nrows, int NTt,
    int mode,
    float* __restrict__ outf, int ldout,
    const float* __restrict__ w2v, const float* __restrict__ b2,
    float* __restrict__ scores) {
  const int tid = threadIdx.x;
  const int l = tid & 63;
  const int w = tid >> 6;
  const int m0 = blockIdx.x * 64 + w * 16;
  const int cb = blockIdx.y * 128;
  const int ntg0 = blockIdx.y * 8;
  const int K = KC * 32;

  f32x4 acc[8];
#pragma unroll
  for (int nt = 0; nt < 8; nt++) acc[nt] = (f32x4){0.f, 0.f, 0.f, 0.f};

  int arow = m0 + (l & 15);
  if (arow >= nrows) arow = nrows - 1;
  const unsigned short* Ap = A + (size_t)arow * K + ((l >> 4) << 3);

#pragma unroll
  for (int kc = 0; kc < KC; kc++) {
    s8v av = *(const s8v*)(Ap + kc * 32);
#pragma unroll
    for (int nt = 0; nt < 8; nt++) {
      const unsigned short* bp = Wf + (((size_t)((kc * NTt) + ntg0 + nt)) << 9) + (l << 3);
      s8v bv = *(const s8v*)bp;
      acc[nt] = __builtin_amdgcn_mfma_f32_16x16x32_bf16(av, bv, acc[nt], 0, 0, 0);
    }
  }

  if (mode == 4) {
    float p[4] = {0.f, 0.f, 0.f, 0.f};
#pragma unroll
    for (int nt = 0; nt < 8; nt++) {
      int col = nt * 16 + (l & 15);
      float bi = bias[col], wv = w2v[col];
#pragma unroll
      for (int reg = 0; reg < 4; reg++)
        p[reg] = fmaf(fast_tanh(acc[nt][reg] + bi), wv, p[reg]);
    }
#pragma unroll
    for (int m = 1; m <= 8; m <<= 1)
#pragma unroll
      for (int reg = 0; reg < 4; reg++) p[reg] += __shfl_xor(p[reg], m);
    if ((l & 15) == 0) {
      float bb = b2[0];
#pragma unroll
      for (int reg = 0; reg < 4; reg++) {
        int row = m0 + ((l >> 4) << 2) + reg;
        if (row < nrows) scores[row] = p[reg] + bb;
      }
    }
    return;
  }

#pragma unroll
  for (int nt = 0; nt < 8; nt++) {
    int col = cb + nt * 16 + (l & 15);
    float bi = bias[col];
#pragma unroll
    for (int reg = 0; reg < 4; reg++) {
      int row = m0 + ((l >> 4) << 2) + reg;
      if (row >= nrows) continue;
      outf[(size_t)row * ldout + col] = acc[nt][reg] + bi;
    }
  }
}

__global__ void k_softmax(const float* __restrict__ sc, float* __restrict__ aw) {
  int bn = blockIdx.x * 256 + threadIdx.x;
  if (bn >= BN_) return;
  float v[T_];
  float m = -1e30f;
#pragma unroll
  for (int t = 0; t < T_; t++) { v[t] = sc[t * BN_ + bn]; m = fmaxf(m, v[t]); }
  float s = 0.f;
#pragma unroll
  for (int t = 0; t < T_; t++) { v[t] = __expf(v[t] - m); s += v[t]; }
  float inv = __builtin_amdgcn_rcpf(s);
#pragma unroll
  for (int t = 0; t < T_; t++) aw[t * BN_ + bn] = v[t] * inv;
}

__global__ void k_wsum(const float* __restrict__ aw, const unsigned short* __restrict__ hs,
                       unsigned short* __restrict__ nf) {
  int idx = blockIdx.x * 256 + threadIdx.x;
  if (idx >= BN_ * H_) return;
  int bn = idx >> 7, f = idx & 127;
  float s = 0.f;
#pragma unroll
  for (int t = 0; t < T_; t++)
    s = fmaf(aw[t * BN_ + bn], bf2f(hs[((size_t)t * BN_ + bn) * H_ + f]), s);
  nf[idx] = f2bf(s);
}

__global__ void k_gru(const float* __restrict__ gi, const float* __restrict__ bhh,
                      float* __restrict__ h, unsigned short* __restrict__ hbf) {
  int idx = blockIdx.x * 256 + threadIdx.x;
  if (idx >= BN_ * H_) return;
  int bn = idx >> 7, j = idx & 127;
  const float* g = gi + (size_t)bn * 384;
  float r = fast_sigmoid(g[j] + bhh[j]);
  float z = fast_sigmoid(g[128 + j] + bhh[128 + j]);
  float n = fast_tanh(g[256 + j] + r * bhh[256 + j]);
  float hv = (1.f - z) * n;  // h0 = 0
  h[idx] = hv;
  hbf[idx] = f2bf(hv);
}

__global__ void k_proj(const float* __restrict__ st, const float* __restrict__ ow,
                       const float* __restrict__ ob, float* __restrict__ out, int fh) {
  int wid = (blockIdx.x * blockDim.x + threadIdx.x) >> 6;
  int lane = threadIdx.x & 63;
  if (wid >= BN_) return;
  float2 a = ((const float2*)(st + (size_t)wid * 128))[lane];
  float2 w = ((const float2*)ow)[lane];
  float s = a.x * w.x + a.y * w.y;
#pragma unroll
  for (int off = 32; off > 0; off >>= 1) s += __shfl_down(s, off);
  if (lane == 0) out[(size_t)wid * FH_ + fh] = s + ob[0];
}

extern "C" void kernel_launch(void* const* d_in, const int* in_sizes, int n_in,
                              void* d_out, int out_size, void* d_ws, size_t ws_size,
                              hipStream_t stream) {
  const float* x       = (const float*)d_in[0];
  const float* gcn_w1  = (const float*)d_in[1];
  const float* gcn_b1  = (const float*)d_in[2];
  const float* gcn_w2  = (const float*)d_in[3];
  const float* gcn_b2  = (const float*)d_in[4];
  const float* gcn_w3  = (const float*)d_in[5];
  const float* gcn_b3  = (const float*)d_in[6];
  const float* att_w1  = (const float*)d_in[7];
  const float* att_b1  = (const float*)d_in[8];
  const float* att_w2  = (const float*)d_in[9];
  const float* att_b2  = (const float*)d_in[10];
  const float* gru_wih = (const float*)d_in[11];
  const float* gru_bih = (const float*)d_in[13];
  const float* gru_bhh = (const float*)d_in[14];
  const float* ode_w1  = (const float*)d_in[15];
  const float* ode_b1  = (const float*)d_in[16];
  const float* ode_w2  = (const float*)d_in[17];
  const float* ode_b2  = (const float*)d_in[18];
  const float* out_w   = (const float*)d_in[19];
  const float* out_b   = (const float*)d_in[20];
  const int*   eidx    = (const int*)d_in[21];
  float* out = (float*)d_out;

  float* wsf = (float*)d_ws;
  size_t off = 0;
  float* gi     = wsf + off; off += (size_t)BN_ * 384;
  float* hst    = wsf + off; off += (size_t)BN_ * H_;
  float* scores = wsf + off; off += (size_t)T_ * BN_;
  float* aw     = wsf + off; off += (size_t)T_ * BN_;
  float* dinv   = wsf + off; off += BN_;
  int2*  ev     = (int2*)(wsf + off); off += (size_t)TOTE_ * 2;
  unsigned short* hseqb = (unsigned short*)(wsf + off); off += (size_t)T_ * BN_ * H_ / 2;
  unsigned short* hbf   = (unsigned short*)(wsf + off); off += (size_t)BN_ * H_ / 2;
  unsigned short* ubf   = (unsigned short*)(wsf + off); off += (size_t)BN_ * H_ / 2;
  unsigned short* t1bf  = (unsigned short*)(wsf + off); off += (size_t)BN_ * H_ / 2;
  unsigned short* rkb   = (unsigned short*)(wsf + off); off += (size_t)BN_ * H_ / 2;
  unsigned short* h1bf  = (unsigned short*)(wsf + off); off += (size_t)BN_ * 64 / 2;
  unsigned short* nfbf  = (unsigned short*)(wsf + off); off += (size_t)BN_ * H_ / 2;
  unsigned short* w2f   = (unsigned short*)(wsf + off); off += 64 * 128 / 2;
  unsigned short* w3f   = (unsigned short*)(wsf + off); off += 128 * 128 / 2;
  unsigned short* aw1f  = (unsigned short*)(wsf + off); off += 128 * 128 / 2;
  unsigned short* ow1f  = (unsigned short*)(wsf + off); off += 128 * 128 / 2;
  unsigned short* ow2f  = (unsigned short*)(wsf + off); off += 128 * 128 / 2;
  unsigned short* wihf  = (unsigned short*)(wsf + off); off += 128 * 384 / 2;
  int* rp  = (int*)(wsf + off); off += BN_ + 1;
  int* cnt = (int*)(wsf + off); off += BN_;
  if (ws_size < off * sizeof(float)) {
    k_sentinel<<<1, 1, 0, stream>>>(out);
    return;
  }

  const int* esrc = eidx;
  const int* edst = eidx + E_;

  // ---- CSR build + weight prep ----
  k_init_cnt<<<(BN_ + 255) / 256, 256, 0, stream>>>(cnt);
  k_count<<<(E_ + 255) / 256, 256, 0, stream>>>(edst, cnt);
  k_dinv<<<(BN_ + 255) / 256, 256, 0, stream>>>(cnt, dinv);
  k_scan<<<1, 1024, 0, stream>>>(cnt, rp);
  k_fill<<<(TOTE_ + 255) / 256, 256, 0, stream>>>(esrc, edst, rp, cnt, ev, dinv);
  k_prep<<<(64 * 128 + 255) / 256, 256, 0, stream>>>(gcn_w2, w2f, 64, 128, 0);
  k_prep<<<(128 * 128 + 255) / 256, 256, 0, stream>>>(gcn_w3, w3f, 128, 128, 0);
  k_prep<<<(128 * 128 + 255) / 256, 256, 0, stream>>>(att_w1, aw1f, 128, 128, 0);
  k_prep<<<(128 * 128 + 255) / 256, 256, 0, stream>>>(ode_w1, ow1f, 128, 128, 0);
  k_prep<<<(128 * 128 + 255) / 256, 256, 0, stream>>>(ode_w2, ow2f, 128, 128, 0);
  k_prep<<<(128 * 384 + 255) / 256, 256, 0, stream>>>(gru_wih, wihf, 128, 384, 1);

  const int gW = BN_ / 4;
  const int gR = (BN_ + 63) / 64;
  const int gE = (BN_ * H_ + 255) / 256;
  const int gF = 1280;  // fused grid: 4 batches x 320 blocks of 16 rows, XCD-swizzled

  // ---- spatial encoder ----
  for (int t = 0; t < T_; t++) {
    k_spl1<<<gW, 256, 0, stream>>>(rp, ev, x, t, gcn_w1, gcn_b1, h1bf);
    k_fused<64><<<gF, 256, 0, stream>>>(rp, ev, h1bf, w2f, gcn_b2, 1, 0, 0.f, 0.f,
                                        t1bf, nullptr, nullptr, nullptr, nullptr,
                                        nullptr, nullptr, nullptr, 0);
    k_fused<128><<<gF, 256, 0, stream>>>(rp, ev, t1bf, w3f, gcn_b3, 1, 0, 0.f, 0.f,
                                         hseqb + (size_t)t * BN_ * H_, nullptr, nullptr,
                                         nullptr, nullptr, nullptr, nullptr, nullptr, 0);
  }

  // ---- temporal attention ----
  k_mgemm<4><<<dim3((T_ * BN_ + 63) / 64, 1), 256, 0, stream>>>(
      hseqb, aw1f, att_b1, T_ * BN_, 8, 4, nullptr, 128, att_w2, att_b2, scores);
  k_softmax<<<(BN_ + 255) / 256, 256, 0, stream>>>(scores, aw);
  k_wsum<<<gE, 256, 0, stream>>>(aw, hseqb, nfbf);

  // ---- GRU ----
  k_mgemm<4><<<dim3(gR, 3), 256, 0, stream>>>(nfbf, wihf, gru_bih, BN_, 24, 0,
                                              gi, 384, nullptr, nullptr, nullptr);
  k_gru<<<gE, 256, 0, stream>>>(gi, gru_bhh, hst, hbf);
  k_proj<<<gW, 256, 0, stream>>>(hst, out_w, out_b, out, 0);

  // ---- graph ODE, RK4: 2 fused dispatches per f-eval ----
  const float dt = (float)FH_ / (float)(FH_ - 1);
  auto f_eval = [&](const unsigned short* inbf, int mode, float c1, float c2, int step) {
    k_fused<128><<<gF, 256, 0, stream>>>(rp, ev, inbf, ow1f, ode_b1, 2, 0, 0.f, 0.f,
                                         t1bf, nullptr, nullptr, nullptr, nullptr,
                                         nullptr, nullptr, nullptr, 0);
    k_fused<128><<<gF, 256, 0, stream>>>(rp, ev, t1bf, ow2f, ode_b2, 2, mode, c1, c2,
                                         nullptr, hbf, rkb, hst,
                                         (mode == 3) ? hbf : ubf,
                                         out_w, out_b, out, step);
  };
  for (int s = 1; s < FH_; s++) {
    f_eval(hbf, 1, 0.5f * dt, 0.f, s);
    f_eval(ubf, 2, 0.5f * dt, 0.f, s);
    f_eval(ubf, 2, dt, 0.f, s);
    f_eval(ubf, 3, 0.f, dt / 6.f, s);
  }
}